// Round 14
// baseline (164.143 us; speedup 1.0000x reference)
//
#include <hip/hip_runtime.h>
#include <hip/hip_bf16.h>
#include <math.h>

// ---------------------------------------------------------------------------
// CgpHmmCell forward: 512 seqs x 2048 steps x 25-state HMM (23 live states).
//
// ROUND-14 = R12's lean permuted-pair pk-fp32 scan (40 inst/step, 68.5 us at
// 16 waves/CU) moved to the 32-waves/CU shape: 1024-thread blocks, CHUNKS=32,
// CLEN=64. Cross-round fit says per-inst cost drops 1.7 -> ~1.15 us/inst
// when occupancy doubles (R6-R9 were slow from inflated inst counts, not
// their shape). LDS 51.3 KB -> 2 blocks/CU = 8 waves/SIMD; VGPR cap 64 via
// __launch_bounds__(1024,8) is safely above the 44 live regs (R4 lesson).
//
// Lessons enforced: R4 never clamp below live set; R6 keep global token
// prefetch; R8/R13 never trade 1 LDS inst for >1 VALU inst (fp32 rows!);
// R11 renorm-16 + x16 prescale; R12 permuted-pair pk math.
// ---------------------------------------------------------------------------

typedef float v2f __attribute__((ext_vector_type(2)));
typedef float v4f __attribute__((ext_vector_type(4)));

#define NSTATES 25
#define NLIVE   23
#define NFLAT   216
#define NPACK   100
#define TLEN    2048
#define NSEQ    512
#define CHUNKS  32
#define CLEN    64

#define LOG16 2.772588722239781f

// pos -> canonical state (pad slot = 23, dead)
__device__ __constant__ int PERMC[24] = {1,4,2,5,3,6,7,10,8,11,9,12,
                                         14,17,15,18,16,19,20,0,21,13,22,23};
// canonical state -> position (live states only)
__device__ __constant__ int POSA[NLIVE] = {19,0,2,4,1,3,5,6,8,10,7,9,11,21,
                                           12,14,16,13,15,17,18,20,22};

// ---------------------------------------------------------------------------
// Compile-time emission map (validated: absmax 0.0 across rounds).
// ---------------------------------------------------------------------------
struct WMap { short m[NSTATES * NFLAT]; };

constexpr WMap make_wmap() {
  WMap w{};
  for (int i = 0; i < NSTATES * NFLAT; i++) w.m[i] = -2;
  const unsigned char ST[29] = {0,1,2,3,4,5,6,7,8,9,10,11,11,12,12,12,13,
                                14,15,16,17,18,19,20,21,22,23,23,24};
  const unsigned char M1[29] = {0x1F,0x1F,0x1F,0x11,0x18,0x14,0x1F,0x1F,0x1F,
                                0x1F,0x0F,0x0F,0x0F,0x08,0x08,0x08,0x0F,
                                0x1F,0x1F,0x1F,0x1F,0x1F,0x1F,0x1F,0x1F,0x1F,
                                0x0F,0x0F,0x20};
  const unsigned char M2[29] = {0x1F,0x1F,0x11,0x18,0x14,0x1F,0x1F,0x1F,0x1F,
                                0x1F,0x0F,0x08,0x08,0x01,0x01,0x04,0x0F,
                                0x1F,0x1F,0x1F,0x1F,0x1F,0x1F,0x1F,0x1F,0x1F,
                                0x0F,0x20,0x20};
  const unsigned char M3[29] = {0x0F,0x01,0x08,0x04,0x0F,0x0F,0x0F,0x0F,0x0F,
                                0x0F,0x08,0x01,0x04,0x01,0x04,0x01,0x0F,
                                0x0F,0x0F,0x0F,0x0F,0x0F,0x0F,0x0F,0x0F,0x0F,
                                0x20,0x20,0x20};
  const unsigned char TR[29] = {1,1,1,0,1,1,1,1,1,1,1,1,1,0,0,0,1,
                                1,1,1,1,1,1,1,1,1,1,1,0};
  int k = 0;
  for (int s = 0; s < 29; s++) {
    for (int c1 = 0; c1 < 6; c1++) {
      if (!((M1[s] >> c1) & 1)) continue;
      for (int c2 = 0; c2 < 6; c2++) {
        if (!((M2[s] >> c2) & 1)) continue;
        if (c1 != 4 && c2 == 4) continue;
        for (int c3 = 0; c3 < 6; c3++) {
          if (!((M3[s] >> c3) & 1)) continue;
          w.m[ST[s] * NFLAT + c1 * 36 + c2 * 6 + c3] =
              TR[s] ? (short)(k++) : (short)-1;
        }
      }
    }
  }
  return w;
}
__device__ __constant__ WMap WMAP = make_wmap();

__device__ __forceinline__ unsigned short f2bf(float x) {  // RNE
  unsigned int u = __float_as_uint(x);
  u += 0x7fffu + ((u >> 16) & 1u);
  return (unsigned short)(u >> 16);
}

struct Wp {
  v2f w01, wA, wB, wC, wD, wE, wF;
  float w4, w5, w8, w11;
};

// ---------------------------------------------------------------------------
// One HMM step in permuted-pair layout, fp32 emission row in registers
// (F[0..5] = positions 0..23). Identical math to R12 (absmax 0.0).
// ---------------------------------------------------------------------------
__device__ __forceinline__ void step_pk(v2f (&Q)[12], const v4f (&F)[6],
                                        const Wp& W) {
  float a0 = Q[9].y,  a3 = Q[2].x,  a6 = Q[2].y,  a9 = Q[5].x;
  float a12 = Q[5].y, a13 = Q[10].y, a16 = Q[8].x, a19 = Q[8].y, a22 = Q[11].x;
  float q9x = Q[9].x, q10x = Q[10].x;   // old a20, a21

  v2f t01 = a0 * W.w01;                  // (n0, n1)
  v2f t44 = a3 * W.wA + a16 * W.wB;      // (n4, n14)
  v2f t77 = a6 * W.wC + a19 * W.wD;      // (n7 partial, n17)
  float n7  = fmaf(a3, W.w4, t77.x);
  v2f tAA = a9 * W.wE + a22 * W.wF;      // (n10 partial, n20)
  float n10 = fmaf(a3, W.w5, fmaf(a6, W.w8, tAA.x));
  float n13 = fmaf(a13, W.w11, a12);

  // aligned shift pairs (transition weight 1.0) * emission pair
  v2f nQ1 = Q[0] * __builtin_shufflevector(F[0], F[0], 2, 3);  // (e2,e5)
  v2f nQ2 = Q[1] * __builtin_shufflevector(F[1], F[1], 0, 1);  // (e3,e6)
  v2f nQ4 = Q[3] * __builtin_shufflevector(F[2], F[2], 0, 1);  // (e8,e11)
  v2f nQ5 = Q[4] * __builtin_shufflevector(F[2], F[2], 2, 3);  // (e9,e12)
  v2f nQ7 = Q[6] * __builtin_shufflevector(F[3], F[3], 2, 3);  // (e15,e18)
  v2f nQ8 = Q[7] * __builtin_shufflevector(F[4], F[4], 0, 1);  // (e16,e19)

  Q[0]  = (v2f){ t01.y * F[0].x, t44.x * F[0].y };   // (n1*e1,  n4*e4)
  Q[3]  = (v2f){ n7    * F[1].z, n10   * F[1].w };   // (n7*e7,  n10*e10)
  Q[6]  = (v2f){ t44.y * F[3].x, t77.y * F[3].y };   // (n14*e14, n17*e17)
  Q[9]  = (v2f){ tAA.y * F[4].z, t01.x * F[4].w };   // (n20*e20, n0*e0)
  Q[10] = (v2f){ q9x   * F[5].x, n13   * F[5].y };   // (a20*e21, n13*e13)
  Q[11].x = q10x * F[5].z;                           // a21*e22 (pad .y stays)
  Q[1] = nQ1; Q[2] = nQ2; Q[4] = nQ4; Q[5] = nQ5; Q[7] = nQ7; Q[8] = nQ8;
}

__device__ __forceinline__ void renorm_pk(v2f (&Q)[12], float& L) {
  v2f acc = ((Q[0] + Q[1]) + (Q[2] + Q[3])) + ((Q[4] + Q[5]) + (Q[6] + Q[7]))
          + ((Q[8] + Q[9]) + (Q[10] + Q[11]));
  float s = acc.x + acc.y;
  if (s > 0.0f) {
    L += __logf(s);
    float r = __fdividef(1.0f, s);
    #pragma unroll
    for (int k = 0; k < 12; k++) Q[k] *= r;
  } else {
    L = -3.0e38f;  // row died; stays dead
  }
}

// load fp32 row for NEXT step (6 ds_read_b128), then compute the CURRENT one
#define LDROW(F, nt_) { int nt = (nt_); \
  const v4f* er = (const v4f*)(sBt + (((c12 << 2) + nt) << 5)); \
  F[0] = er[0]; F[1] = er[1]; F[2] = er[2]; \
  F[3] = er[3]; F[4] = er[4]; F[5] = er[5]; \
  c12 = p2 * 5 + nt; p2 = nt; }
#define LDSTEP(Fn, Fc, nt_) { LDROW(Fn, nt_); step_pk(Q, Fc, W); }

// ---------------------------------------------------------------------------
// One kernel: block = sequence, 1024 thr = 32 chunks x 32 lanes, CLEN=64.
// __launch_bounds__(1024,8): 8 waves/EU -> 2 blocks/CU; VGPR cap 64 > 44 live.
// ---------------------------------------------------------------------------
__global__ __launch_bounds__(1024, 8)
void hmm_kernel(const float* __restrict__ wT, const float* __restrict__ wE,
                const float* __restrict__ wI, const int* __restrict__ tokens,
                float* __restrict__ out) {
  __shared__ __align__(16) float          sBt[NPACK * 32];          // 12800 B
  __shared__ __align__(16) unsigned short sT[CHUNKS * NLIVE * 24];  // 35328 B
  __shared__ float sL[CHUNKS * NLIVE];                              //  2944 B
  __shared__ float sAW[24];
  __shared__ float sI[32];

  const int tid   = threadIdx.x;
  const int seq   = blockIdx.x;
  const int chunk = tid >> 5;
  const int row   = tid & 31;
  const int* trow = tokens + (size_t)seq * TLEN;

  // ---- per-block setup: fp32 emission rows (x16 prescale), PERMUTED order --
  if (chunk < NLIVE) {
    const int st = chunk;
    const int pos = POSA[st];
    float part = 0.0f;
    for (int c = row; c < NFLAT; c += 32) {
      short m = WMAP.m[st * NFLAT + c];
      if (m == -1) part += expf(1.0f);
      else if (m >= 0) part += expf(wE[m]);
    }
    #pragma unroll
    for (int m = 1; m < 32; m <<= 1) part += __shfl_xor(part, m, 32);
    float inv = 16.0f / part;
    for (int i = row; i < NPACK; i += 32) {
      int c12 = i >> 2, nt = i & 3;
      int p1 = c12 / 5, p2v = c12 - 5 * p1;
      int flat = p1 * 36 + p2v * 6 + nt;
      short m = WMAP.m[st * NFLAT + flat];
      float v = 0.0f;
      if (m == -1) v = expf(1.0f);
      else if (m >= 0) v = expf(wE[m]);
      sBt[i * 32 + pos] = v * inv;
    }
  }
  for (int i = tid; i < NPACK; i += 1024) sBt[i * 32 + 23] = 0.0f;  // pad slot
  if (tid == 992) {
    // softmax of multi-entry A rows -> 21 packed weights (validated)
    const float w0 = wT[0], w1 = wT[1], w2 = wT[2], w3 = wT[3], w4 = wT[4];
    const float w5 = wT[5], w6 = wT[6], w7 = wT[7], w8 = wT[8], w9 = wT[9];
    { float e0 = expf(1.0f - w0), e1 = expf(w0), is = 1.0f / (e0 + e1);
      sAW[0] = e0 * is; sAW[1] = e1 * is; }
    { float e4 = expf(w1), e14 = expf(w3);
      float e7 = expf(1.0f - w9 * w9), e10 = expf(1.0f - w9 * w9 * w9);
      float is = 1.0f / (e4 + e14 + e7 + e10);
      sAW[2] = e4 * is;  sAW[3] = e14 * is;
      sAW[4] = e7 * is;  sAW[5] = e10 * is; }
    { float e7 = expf(w2), e17 = expf(w4), e10 = expf(1.0f - w9 * w9);
      float is = 1.0f / (e7 + e17 + e10);
      sAW[6] = e7 * is; sAW[7] = e17 * is; sAW[8] = e10 * is; }
    { float e20 = expf(w5), e10 = expf(1.0f - w5), is = 1.0f / (e20 + e10);
      sAW[9] = e20 * is; sAW[10] = e10 * is; }
    sAW[11] = 0.5f; sAW[12] = 0.5f;   // row 13
    { float e4 = expf(w6), e14 = expf(1.0f - w6), is = 1.0f / (e4 + e14);
      sAW[13] = e4 * is; sAW[14] = e14 * is; }
    { float e7 = expf(w7), e17 = expf(1.0f - w7), is = 1.0f / (e7 + e17);
      sAW[15] = e7 * is; sAW[16] = e17 * is; }
    { float e10 = expf(w8), e20 = expf(1.0f - w8), is = 1.0f / (e10 + e20);
      sAW[17] = e10 * is; sAW[18] = e20 * is; }
    sAW[19] = 0.5f; sAW[20] = 0.5f;
  } else if (tid == 993) {
    float e[9], s = 0.0f;
    for (int i = 0; i < 9; i++) { e[i] = expf(wI[i]); s += e[i]; }
    float inv = 1.0f / s;
    for (int i = 0; i < 9; i++) sI[i] = e[i] * inv;
    for (int i = 9; i < 32; i++) sI[i] = 0.0f;
  }
  __syncthreads();

  // A-weights: wave-uniform -> SGPRs, then packed pairs
  float w[21];
  #pragma unroll
  for (int i = 0; i < 21; i++)
    w[i] = __uint_as_float(
        (unsigned)__builtin_amdgcn_readfirstlane(__float_as_uint(sAW[i])));
  Wp W;
  W.w01 = (v2f){w[0],  w[1]};
  W.wA  = (v2f){w[2],  w[3]};
  W.wB  = (v2f){w[13], w[14]};
  W.wC  = (v2f){w[6],  w[7]};
  W.wD  = (v2f){w[15], w[16]};
  W.wE  = (v2f){w[10], w[9]};
  W.wF  = (v2f){w[17], w[18]};
  W.w4 = w[4]; W.w5 = w[5]; W.w8 = w[8]; W.w11 = w[11];

  // ---- scan: chunk of 64 steps, lane = basis row ----
  const int t0 = chunk * CLEN;

  v2f Q[12];
  #pragma unroll
  for (int k = 0; k < 12; k++) {
    Q[k].x = (row == PERMC[2 * k]) ? 1.0f : 0.0f;
    Q[k].y = (row == PERMC[2 * k + 1]) ? 1.0f : 0.0f;
  }
  float L = 0.0f;

  v4f FA[6], FB[6];
  int c12, p2;
  int4 q0 = *(const int4*)(trow + t0);
  int4 q1 = *(const int4*)(trow + t0 + 4);

  int b = 0;
  if (chunk == 0) {
    // body 0 = steps t = 1..7 (t = 0 folded into the combine's init)
    c12 = 20 + q0.x; p2 = q0.x;
    LDROW(FA, q0.y);
    LDSTEP(FB, FA, q0.z);
    LDSTEP(FA, FB, q0.w);
    LDSTEP(FB, FA, q1.x);
    LDSTEP(FA, FB, q1.y);
    LDSTEP(FB, FA, q1.z);
    LDSTEP(FA, FB, q1.w);
    step_pk(Q, FA, W);
    b = 1;
    q0 = *(const int4*)(trow + 8);
    q1 = *(const int4*)(trow + 12);
  } else {
    int2 pp = *(const int2*)(trow + t0 - 2);   // 8B-aligned (t0 mult of 64)
    c12 = pp.x * 5 + pp.y; p2 = pp.y;
  }

  for (; b < CLEN / 8; b++) {
    int4 n0 = q0, n1 = q1;
    if (b + 1 < CLEN / 8) {               // distance-1 global token prefetch
      n0 = *(const int4*)(trow + t0 + (b + 1) * 8);
      n1 = *(const int4*)(trow + t0 + (b + 1) * 8 + 4);
    }
    LDROW(FA, q0.x);
    LDSTEP(FB, FA, q0.y);
    LDSTEP(FA, FB, q0.z);
    LDSTEP(FB, FA, q0.w);
    LDSTEP(FA, FB, q1.x);
    LDSTEP(FB, FA, q1.y);
    LDSTEP(FA, FB, q1.z);
    LDSTEP(FB, FA, q1.w);
    step_pk(Q, FB, W);
    if (b & 1) renorm_pk(Q, L);           // every 16 steps (x16 prescale)
    q0 = n0; q1 = n1;
  }

  // undo the x16 prescale exactly: chunk 0 ran 63 steps, others 64
  if (L > -1.0e38f) L -= (chunk == 0 ? 63.0f : 64.0f) * LOG16;

  // stash chunk matrix row (bf16, PERMUTED position order) + fp32 L
  if (row < NLIVE) {
    const int base = (chunk * NLIVE + row) * 24;
    #pragma unroll
    for (int k = 0; k < 12; k++) {
      ushort2 p; p.x = f2bf(Q[k].x); p.y = f2bf(Q[k].y);
      *(ushort2*)&sT[base + 2 * k] = p;
    }
    sL[chunk * NLIVE + row] = L;
  }
  __syncthreads();

  // ---- combine (wave 0): fold 32 chunk matrices; lane j = canonical col ----
  if (tid < 64) {
    const int lane = tid;
    const bool act = (lane < NLIVE);

    int jp = 23;                          // lane's PERMUTED position
    #pragma unroll
    for (int pos = 0; pos < 23; pos++)
      if (PERMC[pos] == lane) jp = pos;

    const int tok0 = trow[0];
    const int idx0 = 96 + tok0;           // packed (4,4,tok0)

    float v = act ? sI[lane] * sBt[idx0 * 32 + jp] : 0.0f;
    float s = v;
    #pragma unroll
    for (int m = 1; m < 32; m <<= 1) s += __shfl_xor(s, m, 32);
    float ll = __logf(s) - LOG16;         // undo prescale on step 0
    v = act ? v * __fdividef(1.0f, s) : 0.0f;

    for (int c = 0; c < CHUNKS; c++) {
      float Lj  = act ? sL[c * NLIVE + lane] : -3.0e38f;
      float key = (act && v > 0.0f) ? Lj : -3.0e38f;
      float mx = key;
      #pragma unroll
      for (int m = 1; m < 32; m <<= 1) mx = fmaxf(mx, __shfl_xor(mx, m, 32));
      float wgt = (act && v > 0.0f) ? v * __expf(Lj - mx) : 0.0f;

      float nv = 0.0f;
      #pragma unroll
      for (int r = 0; r < NLIVE; r++) {
        float wr = __shfl(wgt, r, 64);
        nv += wr * __uint_as_float(((unsigned)sT[(c * NLIVE + r) * 24 + jp]) << 16);
      }
      float nva = act ? nv : 0.0f;
      float s2 = nva;
      #pragma unroll
      for (int m = 1; m < 32; m <<= 1) s2 += __shfl_xor(s2, m, 32);
      ll += mx + __logf(s2);
      v = act ? nv * __fdividef(1.0f, s2) : 0.0f;
    }

    if (lane == 0) out[seq] = ll;
  }
}

// ---------------------------------------------------------------------------
extern "C" void kernel_launch(void* const* d_in, const int* in_sizes, int n_in,
                              void* d_out, int out_size, void* d_ws, size_t ws_size,
                              hipStream_t stream) {
  const float* wT = (const float*)d_in[0];   // transition_kernel (10)
  const float* wE = (const float*)d_in[1];   // emission_kernel (5400)
  const float* wI = (const float*)d_in[2];   // init_kernel (25)
  const int* tokens = (const int*)d_in[3];   // (512, 2048) int32
  float* out = (float*)d_out;                // (512,) float32
  (void)d_ws; (void)ws_size;                 // workspace unused

  hmm_kernel<<<NSEQ, 1024, 0, stream>>>(wT, wE, wI, tokens, out);
}

// Round 15
// 134.342 us; speedup vs baseline: 1.2218x; 1.2218x over previous
//
#include <hip/hip_runtime.h>
#include <hip/hip_bf16.h>
#include <math.h>

// ---------------------------------------------------------------------------
// CgpHmmCell forward: 512 seqs x 2048 steps x 25-state HMM (23 live states).
//
// ROUND-15 = R14 (R12's lean permuted-pair pk-fp32 scan in the 32-waves/CU
// shape: 1024 thr, CHUNKS=32, CLEN=64) with the launch-bounds spill fixed:
// __launch_bounds__(1024) ONLY. R14's (1024,8) clamped VGPR to 32 (< 44
// live) -> 219 MB scratch writes, 120 us. HARD RULE after R4/R14: never
// pass the min-waves argument; the natural allocation (R7: 56 VGPR at 1024
// thr) is below the 64-VGPR budget that 32 waves/CU needs anyway.
//
// Lessons enforced: R4/R14 no VGPR clamp; R6 keep global token prefetch;
// R8/R13 never trade 1 LDS inst for >1 VALU inst (fp32 rows);
// R11 renorm-16 + x16 prescale; R12 permuted-pair pk math.
// ---------------------------------------------------------------------------

typedef float v2f __attribute__((ext_vector_type(2)));
typedef float v4f __attribute__((ext_vector_type(4)));

#define NSTATES 25
#define NLIVE   23
#define NFLAT   216
#define NPACK   100
#define TLEN    2048
#define NSEQ    512
#define CHUNKS  32
#define CLEN    64

#define LOG16 2.772588722239781f

// pos -> canonical state (pad slot = 23, dead)
__device__ __constant__ int PERMC[24] = {1,4,2,5,3,6,7,10,8,11,9,12,
                                         14,17,15,18,16,19,20,0,21,13,22,23};
// canonical state -> position (live states only)
__device__ __constant__ int POSA[NLIVE] = {19,0,2,4,1,3,5,6,8,10,7,9,11,21,
                                           12,14,16,13,15,17,18,20,22};

// ---------------------------------------------------------------------------
// Compile-time emission map (validated: absmax 0.0 across rounds).
// ---------------------------------------------------------------------------
struct WMap { short m[NSTATES * NFLAT]; };

constexpr WMap make_wmap() {
  WMap w{};
  for (int i = 0; i < NSTATES * NFLAT; i++) w.m[i] = -2;
  const unsigned char ST[29] = {0,1,2,3,4,5,6,7,8,9,10,11,11,12,12,12,13,
                                14,15,16,17,18,19,20,21,22,23,23,24};
  const unsigned char M1[29] = {0x1F,0x1F,0x1F,0x11,0x18,0x14,0x1F,0x1F,0x1F,
                                0x1F,0x0F,0x0F,0x0F,0x08,0x08,0x08,0x0F,
                                0x1F,0x1F,0x1F,0x1F,0x1F,0x1F,0x1F,0x1F,0x1F,
                                0x0F,0x0F,0x20};
  const unsigned char M2[29] = {0x1F,0x1F,0x11,0x18,0x14,0x1F,0x1F,0x1F,0x1F,
                                0x1F,0x0F,0x08,0x08,0x01,0x01,0x04,0x0F,
                                0x1F,0x1F,0x1F,0x1F,0x1F,0x1F,0x1F,0x1F,0x1F,
                                0x0F,0x20,0x20};
  const unsigned char M3[29] = {0x0F,0x01,0x08,0x04,0x0F,0x0F,0x0F,0x0F,0x0F,
                                0x0F,0x08,0x01,0x04,0x01,0x04,0x01,0x0F,
                                0x0F,0x0F,0x0F,0x0F,0x0F,0x0F,0x0F,0x0F,0x0F,
                                0x20,0x20,0x20};
  const unsigned char TR[29] = {1,1,1,0,1,1,1,1,1,1,1,1,1,0,0,0,1,
                                1,1,1,1,1,1,1,1,1,1,1,0};
  int k = 0;
  for (int s = 0; s < 29; s++) {
    for (int c1 = 0; c1 < 6; c1++) {
      if (!((M1[s] >> c1) & 1)) continue;
      for (int c2 = 0; c2 < 6; c2++) {
        if (!((M2[s] >> c2) & 1)) continue;
        if (c1 != 4 && c2 == 4) continue;
        for (int c3 = 0; c3 < 6; c3++) {
          if (!((M3[s] >> c3) & 1)) continue;
          w.m[ST[s] * NFLAT + c1 * 36 + c2 * 6 + c3] =
              TR[s] ? (short)(k++) : (short)-1;
        }
      }
    }
  }
  return w;
}
__device__ __constant__ WMap WMAP = make_wmap();

__device__ __forceinline__ unsigned short f2bf(float x) {  // RNE
  unsigned int u = __float_as_uint(x);
  u += 0x7fffu + ((u >> 16) & 1u);
  return (unsigned short)(u >> 16);
}

struct Wp {
  v2f w01, wA, wB, wC, wD, wE, wF;
  float w4, w5, w8, w11;
};

// ---------------------------------------------------------------------------
// One HMM step in permuted-pair layout, fp32 emission row in registers
// (F[0..5] = positions 0..23). Identical math to R12 (absmax 0.0).
// ---------------------------------------------------------------------------
__device__ __forceinline__ void step_pk(v2f (&Q)[12], const v4f (&F)[6],
                                        const Wp& W) {
  float a0 = Q[9].y,  a3 = Q[2].x,  a6 = Q[2].y,  a9 = Q[5].x;
  float a12 = Q[5].y, a13 = Q[10].y, a16 = Q[8].x, a19 = Q[8].y, a22 = Q[11].x;
  float q9x = Q[9].x, q10x = Q[10].x;   // old a20, a21

  v2f t01 = a0 * W.w01;                  // (n0, n1)
  v2f t44 = a3 * W.wA + a16 * W.wB;      // (n4, n14)
  v2f t77 = a6 * W.wC + a19 * W.wD;      // (n7 partial, n17)
  float n7  = fmaf(a3, W.w4, t77.x);
  v2f tAA = a9 * W.wE + a22 * W.wF;      // (n10 partial, n20)
  float n10 = fmaf(a3, W.w5, fmaf(a6, W.w8, tAA.x));
  float n13 = fmaf(a13, W.w11, a12);

  // aligned shift pairs (transition weight 1.0) * emission pair
  v2f nQ1 = Q[0] * __builtin_shufflevector(F[0], F[0], 2, 3);  // (e2,e5)
  v2f nQ2 = Q[1] * __builtin_shufflevector(F[1], F[1], 0, 1);  // (e3,e6)
  v2f nQ4 = Q[3] * __builtin_shufflevector(F[2], F[2], 0, 1);  // (e8,e11)
  v2f nQ5 = Q[4] * __builtin_shufflevector(F[2], F[2], 2, 3);  // (e9,e12)
  v2f nQ7 = Q[6] * __builtin_shufflevector(F[3], F[3], 2, 3);  // (e15,e18)
  v2f nQ8 = Q[7] * __builtin_shufflevector(F[4], F[4], 0, 1);  // (e16,e19)

  Q[0]  = (v2f){ t01.y * F[0].x, t44.x * F[0].y };   // (n1*e1,  n4*e4)
  Q[3]  = (v2f){ n7    * F[1].z, n10   * F[1].w };   // (n7*e7,  n10*e10)
  Q[6]  = (v2f){ t44.y * F[3].x, t77.y * F[3].y };   // (n14*e14, n17*e17)
  Q[9]  = (v2f){ tAA.y * F[4].z, t01.x * F[4].w };   // (n20*e20, n0*e0)
  Q[10] = (v2f){ q9x   * F[5].x, n13   * F[5].y };   // (a20*e21, n13*e13)
  Q[11].x = q10x * F[5].z;                           // a21*e22 (pad .y stays)
  Q[1] = nQ1; Q[2] = nQ2; Q[4] = nQ4; Q[5] = nQ5; Q[7] = nQ7; Q[8] = nQ8;
}

__device__ __forceinline__ void renorm_pk(v2f (&Q)[12], float& L) {
  v2f acc = ((Q[0] + Q[1]) + (Q[2] + Q[3])) + ((Q[4] + Q[5]) + (Q[6] + Q[7]))
          + ((Q[8] + Q[9]) + (Q[10] + Q[11]));
  float s = acc.x + acc.y;
  if (s > 0.0f) {
    L += __logf(s);
    float r = __fdividef(1.0f, s);
    #pragma unroll
    for (int k = 0; k < 12; k++) Q[k] *= r;
  } else {
    L = -3.0e38f;  // row died; stays dead
  }
}

// load fp32 row for NEXT step (6 ds_read_b128), then compute the CURRENT one
#define LDROW(F, nt_) { int nt = (nt_); \
  const v4f* er = (const v4f*)(sBt + (((c12 << 2) + nt) << 5)); \
  F[0] = er[0]; F[1] = er[1]; F[2] = er[2]; \
  F[3] = er[3]; F[4] = er[4]; F[5] = er[5]; \
  c12 = p2 * 5 + nt; p2 = nt; }
#define LDSTEP(Fn, Fc, nt_) { LDROW(Fn, nt_); step_pk(Q, Fc, W); }

// ---------------------------------------------------------------------------
// One kernel: block = sequence, 1024 thr = 32 chunks x 32 lanes, CLEN=64.
// __launch_bounds__(1024) ONLY — no min-waves arg (R4/R14 spill lessons).
// ---------------------------------------------------------------------------
__global__ __launch_bounds__(1024)
void hmm_kernel(const float* __restrict__ wT, const float* __restrict__ wE,
                const float* __restrict__ wI, const int* __restrict__ tokens,
                float* __restrict__ out) {
  __shared__ __align__(16) float          sBt[NPACK * 32];          // 12800 B
  __shared__ __align__(16) unsigned short sT[CHUNKS * NLIVE * 24];  // 35328 B
  __shared__ float sL[CHUNKS * NLIVE];                              //  2944 B
  __shared__ float sAW[24];
  __shared__ float sI[32];

  const int tid   = threadIdx.x;
  const int seq   = blockIdx.x;
  const int chunk = tid >> 5;
  const int row   = tid & 31;
  const int* trow = tokens + (size_t)seq * TLEN;

  // ---- per-block setup: fp32 emission rows (x16 prescale), PERMUTED order --
  if (chunk < NLIVE) {
    const int st = chunk;
    const int pos = POSA[st];
    float part = 0.0f;
    for (int c = row; c < NFLAT; c += 32) {
      short m = WMAP.m[st * NFLAT + c];
      if (m == -1) part += expf(1.0f);
      else if (m >= 0) part += expf(wE[m]);
    }
    #pragma unroll
    for (int m = 1; m < 32; m <<= 1) part += __shfl_xor(part, m, 32);
    float inv = 16.0f / part;
    for (int i = row; i < NPACK; i += 32) {
      int c12 = i >> 2, nt = i & 3;
      int p1 = c12 / 5, p2v = c12 - 5 * p1;
      int flat = p1 * 36 + p2v * 6 + nt;
      short m = WMAP.m[st * NFLAT + flat];
      float v = 0.0f;
      if (m == -1) v = expf(1.0f);
      else if (m >= 0) v = expf(wE[m]);
      sBt[i * 32 + pos] = v * inv;
    }
  }
  for (int i = tid; i < NPACK; i += 1024) sBt[i * 32 + 23] = 0.0f;  // pad slot
  if (tid == 992) {
    // softmax of multi-entry A rows -> 21 packed weights (validated)
    const float w0 = wT[0], w1 = wT[1], w2 = wT[2], w3 = wT[3], w4 = wT[4];
    const float w5 = wT[5], w6 = wT[6], w7 = wT[7], w8 = wT[8], w9 = wT[9];
    { float e0 = expf(1.0f - w0), e1 = expf(w0), is = 1.0f / (e0 + e1);
      sAW[0] = e0 * is; sAW[1] = e1 * is; }
    { float e4 = expf(w1), e14 = expf(w3);
      float e7 = expf(1.0f - w9 * w9), e10 = expf(1.0f - w9 * w9 * w9);
      float is = 1.0f / (e4 + e14 + e7 + e10);
      sAW[2] = e4 * is;  sAW[3] = e14 * is;
      sAW[4] = e7 * is;  sAW[5] = e10 * is; }
    { float e7 = expf(w2), e17 = expf(w4), e10 = expf(1.0f - w9 * w9);
      float is = 1.0f / (e7 + e17 + e10);
      sAW[6] = e7 * is; sAW[7] = e17 * is; sAW[8] = e10 * is; }
    { float e20 = expf(w5), e10 = expf(1.0f - w5), is = 1.0f / (e20 + e10);
      sAW[9] = e20 * is; sAW[10] = e10 * is; }
    sAW[11] = 0.5f; sAW[12] = 0.5f;   // row 13
    { float e4 = expf(w6), e14 = expf(1.0f - w6), is = 1.0f / (e4 + e14);
      sAW[13] = e4 * is; sAW[14] = e14 * is; }
    { float e7 = expf(w7), e17 = expf(1.0f - w7), is = 1.0f / (e7 + e17);
      sAW[15] = e7 * is; sAW[16] = e17 * is; }
    { float e10 = expf(w8), e20 = expf(1.0f - w8), is = 1.0f / (e10 + e20);
      sAW[17] = e10 * is; sAW[18] = e20 * is; }
    sAW[19] = 0.5f; sAW[20] = 0.5f;
  } else if (tid == 993) {
    float e[9], s = 0.0f;
    for (int i = 0; i < 9; i++) { e[i] = expf(wI[i]); s += e[i]; }
    float inv = 1.0f / s;
    for (int i = 0; i < 9; i++) sI[i] = e[i] * inv;
    for (int i = 9; i < 32; i++) sI[i] = 0.0f;
  }
  __syncthreads();

  // A-weights: wave-uniform -> SGPRs, then packed pairs
  float w[21];
  #pragma unroll
  for (int i = 0; i < 21; i++)
    w[i] = __uint_as_float(
        (unsigned)__builtin_amdgcn_readfirstlane(__float_as_uint(sAW[i])));
  Wp W;
  W.w01 = (v2f){w[0],  w[1]};
  W.wA  = (v2f){w[2],  w[3]};
  W.wB  = (v2f){w[13], w[14]};
  W.wC  = (v2f){w[6],  w[7]};
  W.wD  = (v2f){w[15], w[16]};
  W.wE  = (v2f){w[10], w[9]};
  W.wF  = (v2f){w[17], w[18]};
  W.w4 = w[4]; W.w5 = w[5]; W.w8 = w[8]; W.w11 = w[11];

  // ---- scan: chunk of 64 steps, lane = basis row ----
  const int t0 = chunk * CLEN;

  v2f Q[12];
  #pragma unroll
  for (int k = 0; k < 12; k++) {
    Q[k].x = (row == PERMC[2 * k]) ? 1.0f : 0.0f;
    Q[k].y = (row == PERMC[2 * k + 1]) ? 1.0f : 0.0f;
  }
  float L = 0.0f;

  v4f FA[6], FB[6];
  int c12, p2;
  int4 q0 = *(const int4*)(trow + t0);
  int4 q1 = *(const int4*)(trow + t0 + 4);

  int b = 0;
  if (chunk == 0) {
    // body 0 = steps t = 1..7 (t = 0 folded into the combine's init)
    c12 = 20 + q0.x; p2 = q0.x;
    LDROW(FA, q0.y);
    LDSTEP(FB, FA, q0.z);
    LDSTEP(FA, FB, q0.w);
    LDSTEP(FB, FA, q1.x);
    LDSTEP(FA, FB, q1.y);
    LDSTEP(FB, FA, q1.z);
    LDSTEP(FA, FB, q1.w);
    step_pk(Q, FA, W);
    b = 1;
    q0 = *(const int4*)(trow + 8);
    q1 = *(const int4*)(trow + 12);
  } else {
    int2 pp = *(const int2*)(trow + t0 - 2);   // 8B-aligned (t0 mult of 64)
    c12 = pp.x * 5 + pp.y; p2 = pp.y;
  }

  for (; b < CLEN / 8; b++) {
    int4 n0 = q0, n1 = q1;
    if (b + 1 < CLEN / 8) {               // distance-1 global token prefetch
      n0 = *(const int4*)(trow + t0 + (b + 1) * 8);
      n1 = *(const int4*)(trow + t0 + (b + 1) * 8 + 4);
    }
    LDROW(FA, q0.x);
    LDSTEP(FB, FA, q0.y);
    LDSTEP(FA, FB, q0.z);
    LDSTEP(FB, FA, q0.w);
    LDSTEP(FA, FB, q1.x);
    LDSTEP(FB, FA, q1.y);
    LDSTEP(FA, FB, q1.z);
    LDSTEP(FB, FA, q1.w);
    step_pk(Q, FB, W);
    if (b & 1) renorm_pk(Q, L);           // every 16 steps (x16 prescale)
    q0 = n0; q1 = n1;
  }

  // undo the x16 prescale exactly: chunk 0 ran 63 steps, others 64
  if (L > -1.0e38f) L -= (chunk == 0 ? 63.0f : 64.0f) * LOG16;

  // stash chunk matrix row (bf16, PERMUTED position order) + fp32 L
  if (row < NLIVE) {
    const int base = (chunk * NLIVE + row) * 24;
    #pragma unroll
    for (int k = 0; k < 12; k++) {
      ushort2 p; p.x = f2bf(Q[k].x); p.y = f2bf(Q[k].y);
      *(ushort2*)&sT[base + 2 * k] = p;
    }
    sL[chunk * NLIVE + row] = L;
  }
  __syncthreads();

  // ---- combine (wave 0): fold 32 chunk matrices; lane j = canonical col ----
  if (tid < 64) {
    const int lane = tid;
    const bool act = (lane < NLIVE);

    int jp = 23;                          // lane's PERMUTED position
    #pragma unroll
    for (int pos = 0; pos < 23; pos++)
      if (PERMC[pos] == lane) jp = pos;

    const int tok0 = trow[0];
    const int idx0 = 96 + tok0;           // packed (4,4,tok0)

    float v = act ? sI[lane] * sBt[idx0 * 32 + jp] : 0.0f;
    float s = v;
    #pragma unroll
    for (int m = 1; m < 32; m <<= 1) s += __shfl_xor(s, m, 32);
    float ll = __logf(s) - LOG16;         // undo prescale on step 0
    v = act ? v * __fdividef(1.0f, s) : 0.0f;

    for (int c = 0; c < CHUNKS; c++) {
      float Lj  = act ? sL[c * NLIVE + lane] : -3.0e38f;
      float key = (act && v > 0.0f) ? Lj : -3.0e38f;
      float mx = key;
      #pragma unroll
      for (int m = 1; m < 32; m <<= 1) mx = fmaxf(mx, __shfl_xor(mx, m, 32));
      float wgt = (act && v > 0.0f) ? v * __expf(Lj - mx) : 0.0f;

      float nv = 0.0f;
      #pragma unroll
      for (int r = 0; r < NLIVE; r++) {
        float wr = __shfl(wgt, r, 64);
        nv += wr * __uint_as_float(((unsigned)sT[(c * NLIVE + r) * 24 + jp]) << 16);
      }
      float nva = act ? nv : 0.0f;
      float s2 = nva;
      #pragma unroll
      for (int m = 1; m < 32; m <<= 1) s2 += __shfl_xor(s2, m, 32);
      ll += mx + __logf(s2);
      v = act ? nv * __fdividef(1.0f, s2) : 0.0f;
    }

    if (lane == 0) out[seq] = ll;
  }
}

// ---------------------------------------------------------------------------
extern "C" void kernel_launch(void* const* d_in, const int* in_sizes, int n_in,
                              void* d_out, int out_size, void* d_ws, size_t ws_size,
                              hipStream_t stream) {
  const float* wT = (const float*)d_in[0];   // transition_kernel (10)
  const float* wE = (const float*)d_in[1];   // emission_kernel (5400)
  const float* wI = (const float*)d_in[2];   // init_kernel (25)
  const int* tokens = (const int*)d_in[3];   // (512, 2048) int32
  float* out = (float*)d_out;                // (512,) float32
  (void)d_ws; (void)ws_size;                 // workspace unused

  hmm_kernel<<<NSEQ, 1024, 0, stream>>>(wT, wE, wI, tokens, out);
}

// Round 16
// 120.697 us; speedup vs baseline: 1.3600x; 1.1131x over previous
//
#include <hip/hip_runtime.h>
#include <hip/hip_bf16.h>
#include <math.h>

// ---------------------------------------------------------------------------
// CgpHmmCell forward: 512 seqs x 2048 steps x 25-state HMM (23 live states).
//
// ROUND-16 = REVERT TO R12 (best measured: kernel 68.5 us, total 121.5 us).
// R12's shape (512 thr = 16 chunks x 32 lanes, CLEN=128, 2 blocks/CU,
// fp32 pitch-32 emission rows, permuted-pair pk-fp32 step, renorm-16 with
// x16 prescale, bf16 chunk matrices, wave-0 combine) is the empirical
// pareto floor:
//   R13 (bf16 rows, 3 LDS reads): 81.5 us — unpack VALU swamps LDS savings
//   R14 (32 waves/CU, (1024,8)):  120 us  — launch-bounds spill (VGPR 32)
//   R15 (32 waves/CU, clean):     82.6 us — same LDS-pipe budget + overhead
// The scan is bound by the per-CU LDS pipe (~96 broadcast ds_read_b128 per
// step-round); VALU cuts below 40 inst/step no longer move the wall.
//
// HARD RULES (from this session): never pass __launch_bounds__ min-waves
// (R4/R14 spills); keep the distance-1 global token prefetch (R6); never
// trade 1 LDS inst for >1 VALU inst (R8/R13); renorm every 16 steps with
// x16 emission prescale is precision-safe (R11, absmax 0.0).
// ---------------------------------------------------------------------------

typedef float v2f __attribute__((ext_vector_type(2)));
typedef float v4f __attribute__((ext_vector_type(4)));

#define NSTATES 25
#define NLIVE   23
#define NFLAT   216
#define NPACK   100
#define TLEN    2048
#define NSEQ    512
#define CHUNKS  16
#define CLEN    128

#define LOG16 2.772588722239781f

// pos -> canonical state (pad slot = 23, dead)
__device__ __constant__ int PERMC[24] = {1,4,2,5,3,6,7,10,8,11,9,12,
                                         14,17,15,18,16,19,20,0,21,13,22,23};
// canonical state -> position (live states only)
__device__ __constant__ int POSA[NLIVE] = {19,0,2,4,1,3,5,6,8,10,7,9,11,21,
                                           12,14,16,13,15,17,18,20,22};

// ---------------------------------------------------------------------------
// Compile-time emission map (validated: absmax 0.0 across rounds).
// ---------------------------------------------------------------------------
struct WMap { short m[NSTATES * NFLAT]; };

constexpr WMap make_wmap() {
  WMap w{};
  for (int i = 0; i < NSTATES * NFLAT; i++) w.m[i] = -2;
  const unsigned char ST[29] = {0,1,2,3,4,5,6,7,8,9,10,11,11,12,12,12,13,
                                14,15,16,17,18,19,20,21,22,23,23,24};
  const unsigned char M1[29] = {0x1F,0x1F,0x1F,0x11,0x18,0x14,0x1F,0x1F,0x1F,
                                0x1F,0x0F,0x0F,0x0F,0x08,0x08,0x08,0x0F,
                                0x1F,0x1F,0x1F,0x1F,0x1F,0x1F,0x1F,0x1F,0x1F,
                                0x0F,0x0F,0x20};
  const unsigned char M2[29] = {0x1F,0x1F,0x11,0x18,0x14,0x1F,0x1F,0x1F,0x1F,
                                0x1F,0x0F,0x08,0x08,0x01,0x01,0x04,0x0F,
                                0x1F,0x1F,0x1F,0x1F,0x1F,0x1F,0x1F,0x1F,0x1F,
                                0x0F,0x20,0x20};
  const unsigned char M3[29] = {0x0F,0x01,0x08,0x04,0x0F,0x0F,0x0F,0x0F,0x0F,
                                0x0F,0x08,0x01,0x04,0x01,0x04,0x01,0x0F,
                                0x0F,0x0F,0x0F,0x0F,0x0F,0x0F,0x0F,0x0F,0x0F,
                                0x20,0x20,0x20};
  const unsigned char TR[29] = {1,1,1,0,1,1,1,1,1,1,1,1,1,0,0,0,1,
                                1,1,1,1,1,1,1,1,1,1,1,0};
  int k = 0;
  for (int s = 0; s < 29; s++) {
    for (int c1 = 0; c1 < 6; c1++) {
      if (!((M1[s] >> c1) & 1)) continue;
      for (int c2 = 0; c2 < 6; c2++) {
        if (!((M2[s] >> c2) & 1)) continue;
        if (c1 != 4 && c2 == 4) continue;
        for (int c3 = 0; c3 < 6; c3++) {
          if (!((M3[s] >> c3) & 1)) continue;
          w.m[ST[s] * NFLAT + c1 * 36 + c2 * 6 + c3] =
              TR[s] ? (short)(k++) : (short)-1;
        }
      }
    }
  }
  return w;
}
__device__ __constant__ WMap WMAP = make_wmap();

__device__ __forceinline__ unsigned short f2bf(float x) {  // RNE
  unsigned int u = __float_as_uint(x);
  u += 0x7fffu + ((u >> 16) & 1u);
  return (unsigned short)(u >> 16);
}

struct Wp {
  v2f w01, wA, wB, wC, wD, wE, wF;
  float w4, w5, w8, w11;
};

// ---------------------------------------------------------------------------
// One HMM step in permuted-pair layout, fp32 emission row in registers
// (F[0..5] = positions 0..23). Validated R12 (absmax 0.0).
// ---------------------------------------------------------------------------
__device__ __forceinline__ void step_pk(v2f (&Q)[12], const v4f (&F)[6],
                                        const Wp& W) {
  float a0 = Q[9].y,  a3 = Q[2].x,  a6 = Q[2].y,  a9 = Q[5].x;
  float a12 = Q[5].y, a13 = Q[10].y, a16 = Q[8].x, a19 = Q[8].y, a22 = Q[11].x;
  float q9x = Q[9].x, q10x = Q[10].x;   // old a20, a21

  v2f t01 = a0 * W.w01;                  // (n0, n1)
  v2f t44 = a3 * W.wA + a16 * W.wB;      // (n4, n14)
  v2f t77 = a6 * W.wC + a19 * W.wD;      // (n7 partial, n17)
  float n7  = fmaf(a3, W.w4, t77.x);
  v2f tAA = a9 * W.wE + a22 * W.wF;      // (n10 partial, n20)
  float n10 = fmaf(a3, W.w5, fmaf(a6, W.w8, tAA.x));
  float n13 = fmaf(a13, W.w11, a12);

  // aligned shift pairs (transition weight 1.0) * emission pair
  v2f nQ1 = Q[0] * __builtin_shufflevector(F[0], F[0], 2, 3);  // (e2,e5)
  v2f nQ2 = Q[1] * __builtin_shufflevector(F[1], F[1], 0, 1);  // (e3,e6)
  v2f nQ4 = Q[3] * __builtin_shufflevector(F[2], F[2], 0, 1);  // (e8,e11)
  v2f nQ5 = Q[4] * __builtin_shufflevector(F[2], F[2], 2, 3);  // (e9,e12)
  v2f nQ7 = Q[6] * __builtin_shufflevector(F[3], F[3], 2, 3);  // (e15,e18)
  v2f nQ8 = Q[7] * __builtin_shufflevector(F[4], F[4], 0, 1);  // (e16,e19)

  Q[0]  = (v2f){ t01.y * F[0].x, t44.x * F[0].y };   // (n1*e1,  n4*e4)
  Q[3]  = (v2f){ n7    * F[1].z, n10   * F[1].w };   // (n7*e7,  n10*e10)
  Q[6]  = (v2f){ t44.y * F[3].x, t77.y * F[3].y };   // (n14*e14, n17*e17)
  Q[9]  = (v2f){ tAA.y * F[4].z, t01.x * F[4].w };   // (n20*e20, n0*e0)
  Q[10] = (v2f){ q9x   * F[5].x, n13   * F[5].y };   // (a20*e21, n13*e13)
  Q[11].x = q10x * F[5].z;                           // a21*e22 (pad .y stays)
  Q[1] = nQ1; Q[2] = nQ2; Q[4] = nQ4; Q[5] = nQ5; Q[7] = nQ7; Q[8] = nQ8;
}

__device__ __forceinline__ void renorm_pk(v2f (&Q)[12], float& L) {
  v2f acc = ((Q[0] + Q[1]) + (Q[2] + Q[3])) + ((Q[4] + Q[5]) + (Q[6] + Q[7]))
          + ((Q[8] + Q[9]) + (Q[10] + Q[11]));
  float s = acc.x + acc.y;
  if (s > 0.0f) {
    L += __logf(s);
    float r = __fdividef(1.0f, s);
    #pragma unroll
    for (int k = 0; k < 12; k++) Q[k] *= r;
  } else {
    L = -3.0e38f;  // row died; stays dead
  }
}

// load fp32 row for NEXT step (6 ds_read_b128), then compute the CURRENT one
#define LDROW(F, nt_) { int nt = (nt_); \
  const v4f* er = (const v4f*)(sBt + (((c12 << 2) + nt) << 5)); \
  F[0] = er[0]; F[1] = er[1]; F[2] = er[2]; \
  F[3] = er[3]; F[4] = er[4]; F[5] = er[5]; \
  c12 = p2 * 5 + nt; p2 = nt; }
#define LDSTEP(Fn, Fc, nt_) { LDROW(Fn, nt_); step_pk(Q, Fc, W); }

// ---------------------------------------------------------------------------
// One kernel: block = sequence, 512 thr = 16 chunks x 32 lanes, CLEN=128.
// ---------------------------------------------------------------------------
__global__ __launch_bounds__(512)
void hmm_kernel(const float* __restrict__ wT, const float* __restrict__ wE,
                const float* __restrict__ wI, const int* __restrict__ tokens,
                float* __restrict__ out) {
  __shared__ __align__(16) float          sBt[NPACK * 32];          // 12800 B
  __shared__ __align__(16) unsigned short sT[CHUNKS * NLIVE * 24];  // 17664 B
  __shared__ float sL[CHUNKS * NLIVE];                              //  1472 B
  __shared__ float sAW[24];
  __shared__ float sI[32];

  const int tid   = threadIdx.x;
  const int seq   = blockIdx.x;
  const int chunk = tid >> 5;
  const int row   = tid & 31;
  const int* trow = tokens + (size_t)seq * TLEN;

  // ---- per-block setup: fp32 emission rows (x16 prescale), PERMUTED order --
  for (int st = chunk; st < NLIVE; st += 16) {
    const int pos = POSA[st];
    float part = 0.0f;
    for (int c = row; c < NFLAT; c += 32) {
      short m = WMAP.m[st * NFLAT + c];
      if (m == -1) part += expf(1.0f);
      else if (m >= 0) part += expf(wE[m]);
    }
    #pragma unroll
    for (int m = 1; m < 32; m <<= 1) part += __shfl_xor(part, m, 32);
    float inv = 16.0f / part;
    for (int i = row; i < NPACK; i += 32) {
      int c12 = i >> 2, nt = i & 3;
      int p1 = c12 / 5, p2v = c12 - 5 * p1;
      int flat = p1 * 36 + p2v * 6 + nt;
      short m = WMAP.m[st * NFLAT + flat];
      float v = 0.0f;
      if (m == -1) v = expf(1.0f);
      else if (m >= 0) v = expf(wE[m]);
      sBt[i * 32 + pos] = v * inv;
    }
  }
  for (int i = tid; i < NPACK; i += 512) sBt[i * 32 + 23] = 0.0f;  // pad slot
  if (tid == 480) {
    // softmax of multi-entry A rows -> 21 packed weights (validated)
    const float w0 = wT[0], w1 = wT[1], w2 = wT[2], w3 = wT[3], w4 = wT[4];
    const float w5 = wT[5], w6 = wT[6], w7 = wT[7], w8 = wT[8], w9 = wT[9];
    { float e0 = expf(1.0f - w0), e1 = expf(w0), is = 1.0f / (e0 + e1);
      sAW[0] = e0 * is; sAW[1] = e1 * is; }
    { float e4 = expf(w1), e14 = expf(w3);
      float e7 = expf(1.0f - w9 * w9), e10 = expf(1.0f - w9 * w9 * w9);
      float is = 1.0f / (e4 + e14 + e7 + e10);
      sAW[2] = e4 * is;  sAW[3] = e14 * is;
      sAW[4] = e7 * is;  sAW[5] = e10 * is; }
    { float e7 = expf(w2), e17 = expf(w4), e10 = expf(1.0f - w9 * w9);
      float is = 1.0f / (e7 + e17 + e10);
      sAW[6] = e7 * is; sAW[7] = e17 * is; sAW[8] = e10 * is; }
    { float e20 = expf(w5), e10 = expf(1.0f - w5), is = 1.0f / (e20 + e10);
      sAW[9] = e20 * is; sAW[10] = e10 * is; }
    sAW[11] = 0.5f; sAW[12] = 0.5f;   // row 13
    { float e4 = expf(w6), e14 = expf(1.0f - w6), is = 1.0f / (e4 + e14);
      sAW[13] = e4 * is; sAW[14] = e14 * is; }
    { float e7 = expf(w7), e17 = expf(1.0f - w7), is = 1.0f / (e7 + e17);
      sAW[15] = e7 * is; sAW[16] = e17 * is; }
    { float e10 = expf(w8), e20 = expf(1.0f - w8), is = 1.0f / (e10 + e20);
      sAW[17] = e10 * is; sAW[18] = e20 * is; }
    sAW[19] = 0.5f; sAW[20] = 0.5f;
  } else if (tid == 481) {
    float e[9], s = 0.0f;
    for (int i = 0; i < 9; i++) { e[i] = expf(wI[i]); s += e[i]; }
    float inv = 1.0f / s;
    for (int i = 0; i < 9; i++) sI[i] = e[i] * inv;
    for (int i = 9; i < 32; i++) sI[i] = 0.0f;
  }
  __syncthreads();

  // A-weights: wave-uniform -> SGPRs, then packed pairs
  float w[21];
  #pragma unroll
  for (int i = 0; i < 21; i++)
    w[i] = __uint_as_float(
        (unsigned)__builtin_amdgcn_readfirstlane(__float_as_uint(sAW[i])));
  Wp W;
  W.w01 = (v2f){w[0],  w[1]};
  W.wA  = (v2f){w[2],  w[3]};
  W.wB  = (v2f){w[13], w[14]};
  W.wC  = (v2f){w[6],  w[7]};
  W.wD  = (v2f){w[15], w[16]};
  W.wE  = (v2f){w[10], w[9]};
  W.wF  = (v2f){w[17], w[18]};
  W.w4 = w[4]; W.w5 = w[5]; W.w8 = w[8]; W.w11 = w[11];

  // ---- scan ----
  const int t0 = chunk * CLEN;

  v2f Q[12];
  #pragma unroll
  for (int k = 0; k < 12; k++) {
    Q[k].x = (row == PERMC[2 * k]) ? 1.0f : 0.0f;
    Q[k].y = (row == PERMC[2 * k + 1]) ? 1.0f : 0.0f;
  }
  float L = 0.0f;

  v4f FA[6], FB[6];
  int c12, p2;
  int4 q0 = *(const int4*)(trow + t0);
  int4 q1 = *(const int4*)(trow + t0 + 4);

  int b = 0;
  if (chunk == 0) {
    // body 0 = steps t = 1..7 (t = 0 folded into the combine's init)
    c12 = 20 + q0.x; p2 = q0.x;
    LDROW(FA, q0.y);
    LDSTEP(FB, FA, q0.z);
    LDSTEP(FA, FB, q0.w);
    LDSTEP(FB, FA, q1.x);
    LDSTEP(FA, FB, q1.y);
    LDSTEP(FB, FA, q1.z);
    LDSTEP(FA, FB, q1.w);
    step_pk(Q, FA, W);
    b = 1;
    q0 = *(const int4*)(trow + 8);
    q1 = *(const int4*)(trow + 12);
  } else {
    int2 pp = *(const int2*)(trow + t0 - 2);
    c12 = pp.x * 5 + pp.y; p2 = pp.y;
  }

  for (; b < CLEN / 8; b++) {
    int4 n0 = q0, n1 = q1;
    if (b + 1 < CLEN / 8) {               // distance-1 global token prefetch
      n0 = *(const int4*)(trow + t0 + (b + 1) * 8);
      n1 = *(const int4*)(trow + t0 + (b + 1) * 8 + 4);
    }
    LDROW(FA, q0.x);
    LDSTEP(FB, FA, q0.y);
    LDSTEP(FA, FB, q0.z);
    LDSTEP(FB, FA, q0.w);
    LDSTEP(FA, FB, q1.x);
    LDSTEP(FB, FA, q1.y);
    LDSTEP(FA, FB, q1.z);
    LDSTEP(FB, FA, q1.w);
    step_pk(Q, FB, W);
    if (b & 1) renorm_pk(Q, L);           // every 16 steps (x16 prescale)
    q0 = n0; q1 = n1;
  }

  // undo the x16 prescale exactly: chunk 0 ran 127 steps, others 128
  if (L > -1.0e38f) L -= (chunk == 0 ? 127.0f : 128.0f) * LOG16;

  // stash chunk matrix row (bf16, PERMUTED position order) + fp32 L
  if (row < NLIVE) {
    const int base = (chunk * NLIVE + row) * 24;
    #pragma unroll
    for (int k = 0; k < 12; k++) {
      ushort2 p; p.x = f2bf(Q[k].x); p.y = f2bf(Q[k].y);
      *(ushort2*)&sT[base + 2 * k] = p;
    }
    sL[chunk * NLIVE + row] = L;
  }
  __syncthreads();

  // ---- combine (wave 0): fold 16 chunk matrices; lane j = canonical col ----
  if (tid < 64) {
    const int lane = tid;
    const bool act = (lane < NLIVE);

    int jp = 23;                          // lane's PERMUTED position
    #pragma unroll
    for (int pos = 0; pos < 23; pos++)
      if (PERMC[pos] == lane) jp = pos;

    const int tok0 = trow[0];
    const int idx0 = 96 + tok0;           // packed (4,4,tok0)

    float v = act ? sI[lane] * sBt[idx0 * 32 + jp] : 0.0f;
    float s = v;
    #pragma unroll
    for (int m = 1; m < 32; m <<= 1) s += __shfl_xor(s, m, 32);
    float ll = __logf(s) - LOG16;         // undo prescale on step 0
    v = act ? v * __fdividef(1.0f, s) : 0.0f;

    for (int c = 0; c < CHUNKS; c++) {
      float Lj  = act ? sL[c * NLIVE + lane] : -3.0e38f;
      float key = (act && v > 0.0f) ? Lj : -3.0e38f;
      float mx = key;
      #pragma unroll
      for (int m = 1; m < 32; m <<= 1) mx = fmaxf(mx, __shfl_xor(mx, m, 32));
      float wgt = (act && v > 0.0f) ? v * __expf(Lj - mx) : 0.0f;

      float nv = 0.0f;
      #pragma unroll
      for (int r = 0; r < NLIVE; r++) {
        float wr = __shfl(wgt, r, 64);
        nv += wr * __uint_as_float(((unsigned)sT[(c * NLIVE + r) * 24 + jp]) << 16);
      }
      float nva = act ? nv : 0.0f;
      float s2 = nva;
      #pragma unroll
      for (int m = 1; m < 32; m <<= 1) s2 += __shfl_xor(s2, m, 32);
      ll += mx + __logf(s2);
      v = act ? nv * __fdividef(1.0f, s2) : 0.0f;
    }

    if (lane == 0) out[seq] = ll;
  }
}

// ---------------------------------------------------------------------------
extern "C" void kernel_launch(void* const* d_in, const int* in_sizes, int n_in,
                              void* d_out, int out_size, void* d_ws, size_t ws_size,
                              hipStream_t stream) {
  const float* wT = (const float*)d_in[0];   // transition_kernel (10)
  const float* wE = (const float*)d_in[1];   // emission_kernel (5400)
  const float* wI = (const float*)d_in[2];   // init_kernel (25)
  const int* tokens = (const int*)d_in[3];   // (512, 2048) int32
  float* out = (float*)d_out;                // (512,) float32
  (void)d_ws; (void)ws_size;                 // workspace unused

  hmm_kernel<<<NSEQ, 512, 0, stream>>>(wT, wE, wI, tokens, out);
}